// Round 3
// baseline (448.216 us; speedup 1.0000x reference)
//
#include <hip/hip_runtime.h>
#include <cstddef>

// Problem dims
#define CI_  64
#define CO_  256
#define DD_  31
#define HH_  96
#define WW_  96
#define HW_  (HH_*WW_)      // 9216
#define DHW_ (DD_*HW_)      // 285696
#define EPSV 1e-5f

// Padded channels-last fp16 input: xt[cig8][pd34][ph98][pw98][ci8]
// (pd = real d + 1; planes 0, 32, 33 are zero — 33 exists for the d-pair tail)
#define PD_   34
#define PH_   98
#define PW_   98
#define PHW_  9604          // 98*98
#define PDHW_ 326536        // 34*9604

// Conv tile: M=256 (2d x 8h x 16w) x N=256, per block. 8 waves: 2 (d) x 4 (N).
// LDS halo: [dd4][row10][cig8][col18][ci8] halves — linear in task order.
#define S_COL 8
#define S_CIG 144           // 18*8
#define S_ROW 1152          // 8*144
#define S_DD  11520         // 10*1152
#define NTASK 5760          // 4*10*8*18 real 16B tasks
#define NTASKP 6144         // padded to 12*512
#define XH_N  (NTASKP*8)    // 49152 halves = 98304 B

#define NTILE 72            // 12 hti * 6 wti per d-pair plane
#define NDP   16            // d-pairs (last covers d=30 only)
#define NBLK  (NTILE*NDP)   // 1152 conv blocks (= 8*144, XCD-exact)
#define GSP   128           // spatial elems per block gate region per co

typedef _Float16 half8   __attribute__((ext_vector_type(8)));
typedef _Float16 half4v  __attribute__((ext_vector_type(4)));
typedef float    float4v __attribute__((ext_vector_type(4)));

__device__ __forceinline__ void gl_lds16(const _Float16* g, _Float16* l) {
  __builtin_amdgcn_global_load_lds(
      (const __attribute__((address_space(1))) unsigned int*)(g),
      (__attribute__((address_space(3))) unsigned int*)(l), 16, 0, 0);
}

// -------- weight repack: w[co][ci][27] fp32 -> wr2[t][kc][cog][quad][lw][ci8] fp16
__global__ __launch_bounds__(256) void repack_w_k(const float* __restrict__ w,
                                                  _Float16* __restrict__ wr2) {
  int idx = blockIdx.x * 256 + threadIdx.x;   // 27*2*16*4*16 = 55296
  if (idx >= 55296) return;
  int lw   = idx & 15;
  int quad = (idx >> 4) & 3;
  int cog  = (idx >> 6) & 15;
  int tkc  = idx >> 10;          // t*2+kc
  int kc   = tkc & 1;
  int t    = tkc >> 1;
  int co   = cog * 16 + lw;
  int cib  = kc * 32 + quad * 8;
  half8 v;
#pragma unroll
  for (int s = 0; s < 8; s++)
    v[s] = (_Float16)w[(size_t)co * 1728 + (size_t)(cib + s) * 27 + t];
  *(half8*)(wr2 + (size_t)idx * 8) = v;
}

// -------- border zeros for padded xt --------
__global__ __launch_bounds__(256) void pad_zero_k(_Float16* __restrict__ xt) {
  int p = blockIdx.x * 256 + threadIdx.x;
  if (p >= PDHW_) return;
  int pd  = p / PHW_;
  int rem = p - pd * PHW_;
  int ph  = rem / PW_;
  int pw  = rem - ph * PW_;
  bool in = (pd >= 1) & (pd <= DD_) & (ph >= 1) & (ph <= HH_) & (pw >= 1) & (pw <= WW_);
  if (in) return;
  half8 z = (half8)(_Float16)0.f;
#pragma unroll
  for (int cig = 0; cig < 8; cig++)
    *(half8*)(xt + ((size_t)cig * PDHW_ + p) * 8) = z;
}

// -------- interior transpose: fp32 NCDHW -> fp16 channels-last, float4-wide ----
__global__ __launch_bounds__(256) void transpose_x_k(const float* __restrict__ x,
                                                     _Float16* __restrict__ xt) {
  int idx = blockIdx.x * 256 + threadIdx.x;   // 31*96*24 = 71424
  if (idx >= 31 * 96 * 24) return;
  int wq  = idx % 24;
  int rem = idx / 24;
  int h   = rem % 96;
  int d   = rem / 96;
  const float* xp = x + (size_t)d * HW_ + (size_t)h * WW_ + wq * 4;
  size_t p0 = (size_t)(d + 1) * PHW_ + (size_t)(h + 1) * PW_ + (wq * 4 + 1);
#pragma unroll 1
  for (int cig = 0; cig < 8; cig++) {
    float4 vv[8];
#pragma unroll
    for (int s = 0; s < 8; s++)
      vv[s] = *(const float4*)(xp + (size_t)(cig * 8 + s) * DHW_);
#pragma unroll
    for (int k = 0; k < 4; k++) {
      half8 o;
#pragma unroll
      for (int s = 0; s < 8; s++) o[s] = (_Float16)(&vv[s].x)[k];
      *(half8*)(xt + ((size_t)cig * PDHW_ + p0 + k) * 8) = o;
    }
  }
}

// -------- conv3d (implicit GEMM, f16 MFMA) + BN + act -> block-private gates ----
// grid: 1152 blocks (XCD-chunk swizzled). block 512 = 8 waves (2 d-planes x 4 N).
// Each wave: M=128 (8h x 16w of its d-plane) x N=64. B traffic per output row
// is HALVED vs the 1-plane block (216 KB/wave covers 128 rows, not 64).
// Single staging phase (global_load_lds direct), ONE barrier, barrier-free K loop.
__global__ __launch_bounds__(512, 2) void conv_mfma_k(
    const _Float16* __restrict__ xt, const _Float16* __restrict__ wr2,
    const float* __restrict__ gamma, const float* __restrict__ beta,
    const float* __restrict__ mean, const float* __restrict__ var,
    _Float16* __restrict__ gates)
{
  __shared__ _Float16 xh[XH_N];

  // XCD-chunked swizzle: 1152 = 8 * 144 exactly (bijective)
  const int bid  = blockIdx.x;
  const int flat = (bid & 7) * 144 + (bid >> 3);
  const int dp   = flat / NTILE;
  const int bx   = flat - dp * NTILE;
  const int d0   = dp * 2;
  const int wti  = bx % 6;
  const int hti  = bx / 6;
  const int h0   = hti * 8, w0 = wti * 16;

  const int tid  = threadIdx.x;
  const int lane = tid & 63;
  const int wave = __builtin_amdgcn_readfirstlane(tid >> 6);
  const int wm   = wave >> 2;        // d-plane (0,1)
  const int wn   = wave & 3;         // co group (64 each)
  const int lw   = lane & 15;        // A: m(spatial w)  B: n(co)
  const int quad = lane >> 4;        // k-group (8 ci)

  // ---- stage halo: 5760 16B tasks (+dup pad), direct global->LDS DMA ----
  // input planes pd = d0..d0+3 (zero plane 33 covers the d-pair tail)
#pragma unroll 1
  for (int it = 0; it < 12; ++it) {
    const int wb   = it * 512 + wave * 64;     // wave-uniform LDS base task
    const int task = wb + lane;
    const int tt   = task < NTASK ? task : (NTASK - 1);  // spare lanes dup
    int col = tt % 18;
    int rc  = tt / 18;
    int cig = rc & 7;
    int dr  = rc >> 3;
    int dd  = dr / 10;
    int row = dr - dd * 10;
    const _Float16* g = xt + (((size_t)cig * PDHW_ + (size_t)(d0 + dd) * PHW_ +
                               (size_t)(h0 + row) * PW_ + (w0 + col)) << 3);
    gl_lds16(g, xh + (size_t)wb * 8);
  }

  float4v acc[8][4];
#pragma unroll
  for (int m = 0; m < 8; m++)
#pragma unroll
    for (int j = 0; j < 4; j++) acc[m][j] = (float4v)0.f;

  __syncthreads();   // vmcnt(0) drain of global_load_lds + barrier

  // ---- K loop: no barriers; waves free-run; 32 MFMA per (t,kc) step ----
  const int abase0 = wm * S_DD + quad * S_CIG + lw * S_COL;
#pragma unroll 1
  for (int t9 = 0; t9 < 9; ++t9) {   // kd*3+kh
    const int kd = t9 / 3;
    const int kh = t9 - kd * 3;
#pragma unroll
    for (int kc = 0; kc < 2; ++kc) {
#pragma unroll
      for (int kw = 0; kw < 3; ++kw) {
        const int t = t9 * 3 + kw;
        const _Float16* bp = wr2 + (((size_t)((t * 2 + kc) * 16 + wn * 4)) << 9) + (lane << 3);
        half8 bf[4];
#pragma unroll
        for (int j = 0; j < 4; ++j) bf[j] = *(const half8*)(bp + ((size_t)j << 9));
        const int ab = abase0 + kd * S_DD + kh * S_ROW + (kc * 4) * S_CIG + kw * S_COL;
#pragma unroll
        for (int m = 0; m < 8; ++m) {
          half8 af = *(const half8*)(xh + ab + m * S_ROW);
#pragma unroll
          for (int j = 0; j < 4; ++j)
            acc[m][j] = __builtin_amdgcn_mfma_f32_16x16x32_f16(af, bf[j], acc[m][j], 0, 0, 0);
        }
      }
    }
  }

  // ---- epilogue: BN + activation, block-private gate region ----
  // gates[((d*72+bx)*256 + co)*128 + sp], sp = h_local*16 + w_local
  const int d = d0 + wm;
  if (d < DD_) {
    _Float16* gb = gates + ((size_t)(d * NTILE + bx) * 256) * GSP;
    const bool istanh = (wn == 0) || (wn == 3);
#pragma unroll
    for (int j = 0; j < 4; j++) {
      const int co = wn * 64 + j * 16 + lw;
      const float s  = gamma[co] * rsqrtf(var[co] + EPSV);
      const float bb = fmaf(-mean[co], s, beta[co]);
#pragma unroll
      for (int m = 0; m < 8; m++) {
        half4v hv;
#pragma unroll
        for (int reg = 0; reg < 4; reg++) {
          float v = fmaf(acc[m][j][reg], s, bb);
          float a;
          if (istanh) {
            float tt = __expf(-2.f * fabsf(v));
            float r  = (1.f - tt) * __builtin_amdgcn_rcpf(1.f + tt);
            a = copysignf(r, v);
          } else {
            a = __builtin_amdgcn_rcpf(1.f + __expf(-v));
          }
          hv[reg] = (_Float16)a;
        }
        // D row index = quad*4+reg -> w_local; m = h_local
        *(half4v*)(gb + (size_t)co * GSP + m * 16 + quad * 4) = hv;
      }
    }
  }
}

// -------- SRU recurrence over d; thread per (c, bx, 4-wide sp); pipelined ----
__global__ __launch_bounds__(256) void recurrence_k(const _Float16* __restrict__ gates,
                                                    float* __restrict__ out) {
  const int idx = blockIdx.x * 256 + threadIdx.x;   // 64*72*32 = 147456
  const int q   = idx & 31;          // sp quad
  const int t2  = idx >> 5;          // c*72 + bx
  const int c   = t2 / NTILE;
  const int bx  = t2 - c * NTILE;
  const int hti = bx / 6, wti = bx - hti * 6;
  const int sp  = q * 4;
  const int h   = hti * 8 + (sp >> 4);
  const int w   = wti * 16 + (sp & 15);

  const size_t DSTR = (size_t)NTILE * 256 * GSP;    // per-d gate stride
  const _Float16* g0 = gates + (size_t)bx * 256 * GSP + sp;
  float* op = out + (size_t)c * DHW_ + (size_t)h * WW_ + w;

#define LD(dv, gate) (*(const half4v*)(g0 + (size_t)(dv) * DSTR + (size_t)(c + ((gate) << 6)) * GSP))

  // d = 0 (peeled): C = 1 - f
  half4v cf = LD(0, 1), cr = LD(0, 2), cx = LD(0, 3);
  half4v nwx = LD(1, 0), nf = LD(1, 1), nr = LD(1, 2), nx = LD(1, 3);
  float C[4];
  {
    float4 st;
#pragma unroll
    for (int k = 0; k < 4; k++) {
      C[k] = 1.f - (float)cf[k];
      float r0 = (float)cr[k], x0 = (float)cx[k];
      (&st.x)[k] = fmaf(r0, C[k] - x0, x0);
    }
    *(float4*)op = st;
  }
#pragma unroll 1
  for (int d = 1; d < DD_; d++) {
    half4v cwx = nwx; cf = nf; cr = nr; cx = nx;
    if (d < DD_ - 1) {                 // prefetch d+1 while computing d
      nwx = LD(d + 1, 0); nf = LD(d + 1, 1);
      nr  = LD(d + 1, 2); nx = LD(d + 1, 3);
    }
    float4 st;
#pragma unroll
    for (int k = 0; k < 4; k++) {
      float wx0 = (float)cwx[k], f0 = (float)cf[k], r0 = (float)cr[k], x0 = (float)cx[k];
      C[k] = fmaf(f0, C[k] - wx0, wx0);
      (&st.x)[k] = fmaf(r0, C[k] - x0, x0);
    }
    *(float4*)(op + (size_t)d * HW_) = st;
  }
#undef LD
}

extern "C" void kernel_launch(void* const* d_in, const int* in_sizes, int n_in,
                              void* d_out, int out_size, void* d_ws, size_t ws_size,
                              hipStream_t stream) {
  const float* x     = (const float*)d_in[0];
  const float* w     = (const float*)d_in[1];
  const float* gamma = (const float*)d_in[2];
  const float* beta  = (const float*)d_in[3];
  const float* mean  = (const float*)d_in[4];
  const float* var   = (const float*)d_in[5];
  float* out = (float*)d_out;

  // ws: [wr2: 884736 B][xt: 8*326536*16 = 41796608 B][gates: 31*72*256*128*2 B]
  _Float16* wr2   = (_Float16*)d_ws;
  _Float16* xt    = (_Float16*)((char*)d_ws + 884736);
  _Float16* gates = (_Float16*)((char*)d_ws + 884736 + 41796608);

  repack_w_k<<<216, 256, 0, stream>>>(w, wr2);
  pad_zero_k<<<(PDHW_ + 255) / 256, 256, 0, stream>>>(xt);
  transpose_x_k<<<(31 * 96 * 24 + 255) / 256, 256, 0, stream>>>(x, xt);
  conv_mfma_k<<<NBLK, 512, 0, stream>>>(xt, wr2, gamma, beta, mean, var, gates);
  recurrence_k<<<(64 * NTILE * 32) / 256, 256, 0, stream>>>(gates, out);
}

// Round 4
// 421.477 us; speedup vs baseline: 1.0634x; 1.0634x over previous
//
#include <hip/hip_runtime.h>
#include <cstddef>

// Problem dims
#define CI_  64
#define CO_  256
#define DD_  31
#define HH_  96
#define WW_  96
#define HW_  (HH_*WW_)      // 9216
#define DHW_ (DD_*HW_)      // 285696
#define EPSV 1e-5f

// Padded channels-last fp16 input: xt[cig8][pd33][ph98][pw98][ci8]
#define PD_   33
#define PH_   98
#define PW_   98
#define PHW_  9604          // 98*98
#define PDHW_ 316932        // 33*9604

// Conv tile: M=128 (8h x 16w) x N=256, one d per block. 8 waves: 2 (M) x 4 (N).
// LDS halo: [dd3][row10][cig8][col18][ci8] halves — linear in task order.
#define S_COL 8
#define S_CIG 144           // 18*8
#define S_ROW 1152          // 8*144
#define S_DD  11520         // 10*1152
#define NTASK 4320          // 3*10*8*18 real 16B tasks
#define NTASKP 4352         // padded
#define XH_N  (NTASKP*8)    // 34816 halves = 69632 B

#define NTILE 72            // 12 hti * 6 wti per d-plane
#define NBLK  (NTILE*DD_)   // 2232 conv blocks (= 8*279, XCD-exact)
#define GSP   128           // spatial elems per block gate region per co

typedef _Float16 half8   __attribute__((ext_vector_type(8)));
typedef _Float16 half4v  __attribute__((ext_vector_type(4)));
typedef float    float4v __attribute__((ext_vector_type(4)));

__device__ __forceinline__ void gl_lds16(const _Float16* g, _Float16* l) {
  __builtin_amdgcn_global_load_lds(
      (const __attribute__((address_space(1))) unsigned int*)(g),
      (__attribute__((address_space(3))) unsigned int*)(l), 16, 0, 0);
}

// -------- weight repack: w[co][ci][27] fp32 -> wr2[t][kc][cog][quad][lw][ci8] fp16
__global__ __launch_bounds__(256) void repack_w_k(const float* __restrict__ w,
                                                  _Float16* __restrict__ wr2) {
  int idx = blockIdx.x * 256 + threadIdx.x;   // 27*2*16*4*16 = 55296
  if (idx >= 55296) return;
  int lw   = idx & 15;
  int quad = (idx >> 4) & 3;
  int cog  = (idx >> 6) & 15;
  int tkc  = idx >> 10;          // t*2+kc
  int kc   = tkc & 1;
  int t    = tkc >> 1;
  int co   = cog * 16 + lw;
  int cib  = kc * 32 + quad * 8;
  half8 v;
#pragma unroll
  for (int s = 0; s < 8; s++)
    v[s] = (_Float16)w[(size_t)co * 1728 + (size_t)(cib + s) * 27 + t];
  *(half8*)(wr2 + (size_t)idx * 8) = v;
}

// -------- border zeros for padded xt --------
__global__ __launch_bounds__(256) void pad_zero_k(_Float16* __restrict__ xt) {
  int p = blockIdx.x * 256 + threadIdx.x;
  if (p >= PDHW_) return;
  int pd  = p / PHW_;
  int rem = p - pd * PHW_;
  int ph  = rem / PW_;
  int pw  = rem - ph * PW_;
  bool in = (pd >= 1) & (pd <= DD_) & (ph >= 1) & (ph <= HH_) & (pw >= 1) & (pw <= WW_);
  if (in) return;
  half8 z = (half8)(_Float16)0.f;
#pragma unroll
  for (int cig = 0; cig < 8; cig++)
    *(half8*)(xt + ((size_t)cig * PDHW_ + p) * 8) = z;
}

// -------- interior transpose: fp32 NCDHW -> fp16 channels-last, float4-wide ----
__global__ __launch_bounds__(256) void transpose_x_k(const float* __restrict__ x,
                                                     _Float16* __restrict__ xt) {
  int idx = blockIdx.x * 256 + threadIdx.x;   // 31*96*24 = 71424
  if (idx >= 31 * 96 * 24) return;
  int wq  = idx % 24;
  int rem = idx / 24;
  int h   = rem % 96;
  int d   = rem / 96;
  const float* xp = x + (size_t)d * HW_ + (size_t)h * WW_ + wq * 4;
  size_t p0 = (size_t)(d + 1) * PHW_ + (size_t)(h + 1) * PW_ + (wq * 4 + 1);
#pragma unroll 1
  for (int cig = 0; cig < 8; cig++) {
    float4 vv[8];
#pragma unroll
    for (int s = 0; s < 8; s++)
      vv[s] = *(const float4*)(xp + (size_t)(cig * 8 + s) * DHW_);
#pragma unroll
    for (int k = 0; k < 4; k++) {
      half8 o;
#pragma unroll
      for (int s = 0; s < 8; s++) o[s] = (_Float16)(&vv[s].x)[k];
      *(half8*)(xt + ((size_t)cig * PDHW_ + p0 + k) * 8) = o;
    }
  }
}

// -------- conv3d (implicit GEMM, f16 MFMA) + BN -> block-private RAW gates ----
// grid: 2232 blocks (XCD-chunk swizzled). block 512 = 8 waves (2 M x 4 N).
// Single staging phase (global_load_lds direct), ONE barrier, barrier-free K
// loop with register double-buffered B prefetch (1 step lookahead).
// Activation (tanh/sigmoid) is deferred to the recurrence kernel.
__global__ __launch_bounds__(512, 4) void conv_mfma_k(
    const _Float16* __restrict__ xt, const _Float16* __restrict__ wr2,
    const float* __restrict__ gamma, const float* __restrict__ beta,
    const float* __restrict__ mean, const float* __restrict__ var,
    _Float16* __restrict__ gates)
{
  __shared__ _Float16 xh[XH_N];

  // XCD-chunked swizzle: 2232 = 8 * 279 exactly (bijective)
  const int bid  = blockIdx.x;
  const int flat = (bid & 7) * 279 + (bid >> 3);
  const int d    = flat / NTILE;
  const int bx   = flat - d * NTILE;
  const int wti  = bx % 6;
  const int hti  = bx / 6;
  const int h0   = hti * 8, w0 = wti * 16;

  const int tid  = threadIdx.x;
  const int lane = tid & 63;
  const int wave = __builtin_amdgcn_readfirstlane(tid >> 6);
  const int wm   = wave >> 2;        // M half (0,1)
  const int wn   = wave & 3;         // co group (64 each)
  const int lw   = lane & 15;        // A: m(spatial w)  B: n(co)
  const int quad = lane >> 4;        // k-group (8 ci)

  // ---- stage halo: 4352 16B tasks, direct global->LDS DMA, all in-bounds ----
#pragma unroll 1
  for (int it = 0; it < 9; ++it) {
    const int wb = it * 512 + wave * 64;       // wave-uniform LDS base task
    if (wb < NTASKP) {
      const int task = wb + lane;
      const int tt   = task < NTASK ? task : (NTASK - 1);  // spare lanes dup
      int col = tt % 18;
      int rc  = tt / 18;
      int cig = rc & 7;
      int dr  = rc >> 3;
      int dd  = dr / 10;
      int row = dr - dd * 10;
      const _Float16* g = xt + (((size_t)cig * PDHW_ + (size_t)(d + dd) * PHW_ +
                                 (size_t)(h0 + row) * PW_ + (w0 + col)) << 3);
      gl_lds16(g, xh + (size_t)wb * 8);
    }
  }

  float4v acc[4][4];
#pragma unroll
  for (int m = 0; m < 4; m++)
#pragma unroll
    for (int j = 0; j < 4; j++) acc[m][j] = (float4v)0.f;

  __syncthreads();   // vmcnt(0) drain of global_load_lds + barrier

  // ---- K loop: 54 steps (t9 x kc x kw), B reg-double-buffered, no barriers --
  const int abase0 = quad * S_CIG + lw * S_COL + (wm * 4) * S_ROW;

  // step s -> (t9, kc, kw): t9 = s/6, kc = (s%6)/3, kw = s%3
#define LOADB(bf, s)                                                          \
  {                                                                           \
    const int t9_ = (s) / 6, sub_ = (s) - 6 * t9_;                            \
    const int kc_ = sub_ / 3, kw_ = sub_ - 3 * kc_;                           \
    const int t_  = t9_ * 3 + kw_;                                            \
    const _Float16* bp_ =                                                     \
        wr2 + (((size_t)((t_ * 2 + kc_) * 16 + wn * 4)) << 9) + (lane << 3);  \
    bf[0] = *(const half8*)(bp_);                                             \
    bf[1] = *(const half8*)(bp_ + (1 << 9));                                  \
    bf[2] = *(const half8*)(bp_ + (2 << 9));                                  \
    bf[3] = *(const half8*)(bp_ + (3 << 9));                                  \
  }

#define STEP(s, bf)                                                           \
  {                                                                           \
    const int t9_ = (s) / 6, sub_ = (s) - 6 * t9_;                            \
    const int kc_ = sub_ / 3, kw_ = sub_ - 3 * kc_;                           \
    const int kd_ = t9_ / 3, kh_ = t9_ - 3 * kd_;                             \
    const int ab_ = abase0 + kd_ * S_DD + kh_ * S_ROW + kc_ * (4 * S_CIG) +   \
                    kw_ * S_COL;                                              \
    half8 af0 = *(const half8*)(xh + ab_);                                    \
    half8 af1 = *(const half8*)(xh + ab_ + S_ROW);                            \
    half8 af2 = *(const half8*)(xh + ab_ + 2 * S_ROW);                        \
    half8 af3 = *(const half8*)(xh + ab_ + 3 * S_ROW);                        \
    __builtin_amdgcn_s_setprio(1);                                            \
    _Pragma("unroll")                                                         \
    for (int j = 0; j < 4; ++j) {                                             \
      acc[0][j] = __builtin_amdgcn_mfma_f32_16x16x32_f16(af0, bf[j], acc[0][j], 0, 0, 0); \
      acc[1][j] = __builtin_amdgcn_mfma_f32_16x16x32_f16(af1, bf[j], acc[1][j], 0, 0, 0); \
      acc[2][j] = __builtin_amdgcn_mfma_f32_16x16x32_f16(af2, bf[j], acc[2][j], 0, 0, 0); \
      acc[3][j] = __builtin_amdgcn_mfma_f32_16x16x32_f16(af3, bf[j], acc[3][j], 0, 0, 0); \
    }                                                                         \
    __builtin_amdgcn_s_setprio(0);                                            \
  }

  half8 bfa[4], bfb[4];
  LOADB(bfa, 0)
#pragma unroll 1
  for (int i = 0; i < 27; ++i) {
    const int s0 = 2 * i;
    LOADB(bfb, s0 + 1)
    STEP(s0, bfa)
    if (i < 26) LOADB(bfa, s0 + 2)
    STEP(s0 + 1, bfb)
  }
#undef LOADB
#undef STEP

  // ---- epilogue: BN only (fma + cvt), raw gates out; act deferred ----
  // gates[((d*72+bx)*256 + co)*128 + sp], sp = h_local*16 + w_local
  _Float16* gb = gates + ((size_t)(d * NTILE + bx) * 256) * GSP;
#pragma unroll
  for (int j = 0; j < 4; j++) {
    const int co = wn * 64 + j * 16 + lw;
    const float s  = gamma[co] * rsqrtf(var[co] + EPSV);
    const float bb = fmaf(-mean[co], s, beta[co]);
#pragma unroll
    for (int m = 0; m < 4; m++) {
      half4v hv;
#pragma unroll
      for (int reg = 0; reg < 4; reg++)
        hv[reg] = (_Float16)fmaf(acc[m][j][reg], s, bb);
      // D row index = quad*4+reg -> w_local; (wm*4+m) = h_local
      *(half4v*)(gb + (size_t)co * GSP + (wm * 4 + m) * 16 + quad * 4) = hv;
    }
  }
}

// -------- SRU recurrence over d; act (tanh/sigm) fused here; pipelined ----
__device__ __forceinline__ float tanh_f(float v) {
  float t = __expf(-2.f * fabsf(v));
  return copysignf((1.f - t) * __builtin_amdgcn_rcpf(1.f + t), v);
}
__device__ __forceinline__ float sigm_f(float v) {
  return __builtin_amdgcn_rcpf(1.f + __expf(-v));
}

__global__ __launch_bounds__(256) void recurrence_k(const _Float16* __restrict__ gates,
                                                    float* __restrict__ out) {
  const int idx = blockIdx.x * 256 + threadIdx.x;   // 64*72*32 = 147456
  const int q   = idx & 31;          // sp quad
  const int t2  = idx >> 5;          // c*72 + bx
  const int c   = t2 / NTILE;
  const int bx  = t2 - c * NTILE;
  const int hti = bx / 6, wti = bx - hti * 6;
  const int sp  = q * 4;
  const int h   = hti * 8 + (sp >> 4);
  const int w   = wti * 16 + (sp & 15);

  const size_t DSTR = (size_t)NTILE * 256 * GSP;    // per-d gate stride
  const _Float16* g0 = gates + (size_t)bx * 256 * GSP + sp;
  float* op = out + (size_t)c * DHW_ + (size_t)h * WW_ + w;

#define LD(dv, gate) (*(const half4v*)(g0 + (size_t)(dv) * DSTR + (size_t)(c + ((gate) << 6)) * GSP))

  // d = 0 (peeled): C = 1 - sigm(f)
  half4v cf = LD(0, 1), cr = LD(0, 2), cx = LD(0, 3);
  half4v nwx = LD(1, 0), nf = LD(1, 1), nr = LD(1, 2), nx = LD(1, 3);
  float C[4];
  {
    float4 st;
#pragma unroll
    for (int k = 0; k < 4; k++) {
      C[k] = 1.f - sigm_f((float)cf[k]);
      float r0 = sigm_f((float)cr[k]), x0 = tanh_f((float)cx[k]);
      (&st.x)[k] = fmaf(r0, C[k] - x0, x0);
    }
    *(float4*)op = st;
  }
#pragma unroll 1
  for (int d = 1; d < DD_; d++) {
    half4v cwx = nwx; cf = nf; cr = nr; cx = nx;
    if (d < DD_ - 1) {                 // prefetch d+1 while computing d
      nwx = LD(d + 1, 0); nf = LD(d + 1, 1);
      nr  = LD(d + 1, 2); nx = LD(d + 1, 3);
    }
    float4 st;
#pragma unroll
    for (int k = 0; k < 4; k++) {
      float wx0 = tanh_f((float)cwx[k]);
      float f0  = sigm_f((float)cf[k]);
      float r0  = sigm_f((float)cr[k]);
      float x0  = tanh_f((float)cx[k]);
      C[k] = fmaf(f0, C[k] - wx0, wx0);
      (&st.x)[k] = fmaf(r0, C[k] - x0, x0);
    }
    *(float4*)(op + (size_t)d * HW_) = st;
  }
#undef LD
}

extern "C" void kernel_launch(void* const* d_in, const int* in_sizes, int n_in,
                              void* d_out, int out_size, void* d_ws, size_t ws_size,
                              hipStream_t stream) {
  const float* x     = (const float*)d_in[0];
  const float* w     = (const float*)d_in[1];
  const float* gamma = (const float*)d_in[2];
  const float* beta  = (const float*)d_in[3];
  const float* mean  = (const float*)d_in[4];
  const float* var   = (const float*)d_in[5];
  float* out = (float*)d_out;

  // ws: [wr2: 884736 B][xt: 8*316932*16 = 40567296 B][gates: 31*72*256*128*2 B]
  _Float16* wr2   = (_Float16*)d_ws;
  _Float16* xt    = (_Float16*)((char*)d_ws + 884736);
  _Float16* gates = (_Float16*)((char*)d_ws + 884736 + 40567296);

  repack_w_k<<<216, 256, 0, stream>>>(w, wr2);
  pad_zero_k<<<(PDHW_ + 255) / 256, 256, 0, stream>>>(xt);
  transpose_x_k<<<(31 * 96 * 24 + 255) / 256, 256, 0, stream>>>(x, xt);
  conv_mfma_k<<<NBLK, 512, 0, stream>>>(xt, wr2, gamma, beta, mean, var, gates);
  recurrence_k<<<(64 * NTILE * 32) / 256, 256, 0, stream>>>(gates, out);
}